// Round 12
// baseline (489.780 us; speedup 1.0000x reference)
//
#include <hip/hip_runtime.h>

#define NUM_SYM 50000
#define NUM_HERB 50000
#define N_NODES (NUM_SYM + NUM_HERB)
#define DIM 128
#define NB ((N_NODES + 127) / 128)           // 782 buckets of 128 rows
#define CHUNK 4096                           // edges per scatter block
#define PAD 16                               // ints per bucket cursor (64B line)
#define LDSCAP 6144                          // max bucket slots held in LDS (24KB)

typedef float floatx4 __attribute__((ext_vector_type(4)));

__device__ __forceinline__ float bf2f(unsigned short u) {
    return __uint_as_float((unsigned)u << 16);
}
__device__ __forceinline__ unsigned short f2bf(float f) {
    unsigned u = __float_as_uint(f);
    unsigned r = (u + 0x7FFFu + ((u >> 16) & 1u)) >> 16;   // round-to-nearest-even
    return (unsigned short)r;
}

// ------- fused: gapped bucket scatter (blocks < EB) + bf16 convert -------
// Each bucket owns a fixed CAP-slot region at bucket*CAP. CAP = 1.125x mean
// (+8 sigma for Poisson bucket sizes); E >= 2^22 or CAP > LDSCAP falls back.
// Record (round-9 verified split form): key = (row_low7 << 17) | col (4B),
// val = bf16 (2B). Convert blocks (>= EB) stream sym/herb -> bf16 table.
__global__ __launch_bounds__(1024) void scatter_and_convert(
    const int* __restrict__ rows, const int* __restrict__ cols,
    const float* __restrict__ vals, int E, int CAP, int EB,
    const float* __restrict__ sym, const float* __restrict__ herb,
    int* __restrict__ cur, int* __restrict__ keys, ushort* __restrict__ bvals,
    ushort* __restrict__ xbf)
{
    __shared__ int lh[NB];
    __shared__ int labs[NB];
    if ((int)blockIdx.x >= EB) {
        // ---- bf16 conversion part ----
        int i = ((int)blockIdx.x - EB) * 1024 + threadIdx.x;   // float4 index
        const int n4 = N_NODES * DIM / 4;
        if (i >= n4) return;
        const int sym4 = NUM_SYM * DIM / 4;
        float4 v = (i < sym4) ? reinterpret_cast<const float4*>(sym)[i]
                              : reinterpret_cast<const float4*>(herb)[i - sym4];
        ushort4 o;
        o.x = f2bf(v.x); o.y = f2bf(v.y); o.z = f2bf(v.z); o.w = f2bf(v.w);
        reinterpret_cast<ushort4*>(xbf)[i] = o;
        return;
    }
    // ---- scatter part ----
    for (int i = threadIdx.x; i < NB; i += 1024) lh[i] = 0;
    __syncthreads();
    int start = blockIdx.x * CHUNK;
    int end   = min(start + CHUNK, E);
    for (int e = start + threadIdx.x; e < end; e += 1024)
        atomicAdd(&lh[rows[e] >> 7], 1);
    __syncthreads();
    for (int i = threadIdx.x; i < NB; i += 1024) {
        int c = lh[i];
        int resv = c ? atomicAdd(&cur[i * PAD], c) : 0;
        labs[i] = i * CAP + resv;                // <= NB*CAP ~ 4.8M, int ok
        lh[i] = 0;                               // reuse as local cursor
    }
    __syncthreads();
    for (int e = start + threadIdx.x; e < end; e += 1024) {
        int r = rows[e];
        int k = r >> 7;
        int pos = labs[k] + atomicAdd(&lh[k], 1);
        keys[pos]  = ((r & 127) << 17) | cols[e];
        bvals[pos] = f2bf(vals[e]);
    }
}

// ------- fused per-bucket sort + pull SpMM (one block per 128-row bucket) --
// Phase A: register-stage the bucket's slots (<= 6 records/thread, static
// unroll), build the row-sorted packed CSR in LDS via int LDS atomics
// (int LDS atomics were fine in all prior rounds; only the FP-accumulate
// family stalled -- here accumulation stays in registers, exactly the
// verified pull structure). Phase B: byte-level-identical 8-deep gather
// loop, reading CSR records from LDS instead of global. This deletes the
// separate slots_to_csr dispatch and the csr global write + 2x read.
// MODE 0: write e1bf (bf16 gather table for layer 2); MODE 1: fused mean.
template <int MODE>
__global__ __launch_bounds__(1024, 8) void spmm_bucket(
    const int* __restrict__ keys, const ushort* __restrict__ bvals,
    const int* __restrict__ cur, int CAP,
    const ushort* __restrict__ xbf,
    const float* __restrict__ sym, const float* __restrict__ herb,
    const ushort* __restrict__ e1bf,
    void* __restrict__ outp)
{
    __shared__ int csrl[LDSCAP];          // 24 KB packed CSR records
    __shared__ int h[128];                // hist / cursor
    __shared__ int rs[129];               // row starts (exclusive) + end
    int b = blockIdx.x, t = threadIdx.x;
    int n = cur[b * PAD];
    if (n > CAP) n = CAP;                 // LDS-bound safety (overflow ~impossible)
    size_t sb = (size_t)b * CAP;

    // --- phase A: stage records, hist, scan, place into LDS CSR ---
    int    k[6];
    ushort w[6];
    #pragma unroll
    for (int q = 0; q < 6; ++q) {
        int j = t + (q << 10);
        if (j < n) { k[q] = keys[sb + j]; w[q] = bvals[sb + j]; }
        else       { k[q] = -1; }
    }
    if (t < 128) h[t] = 0;
    __syncthreads();
    #pragma unroll
    for (int q = 0; q < 6; ++q)
        if (k[q] != -1) atomicAdd(&h[(unsigned)k[q] >> 17], 1);
    __syncthreads();
    int v = (t < 128) ? h[t] : 0;
    for (int o = 1; o < 128; o <<= 1) {   // inclusive scan, 128 bins
        int x = (t < 128 && t >= o) ? h[t - o] : 0;
        __syncthreads();
        if (t < 128) h[t] += x;
        __syncthreads();
    }
    if (t < 128) rs[t] = h[t] - v;
    if (t == 0)  rs[128] = n;
    __syncthreads();
    if (t < 128) h[t] -= v;               // exclusive -> cursor
    __syncthreads();
    #pragma unroll
    for (int q = 0; q < 6; ++q)
        if (k[q] != -1) {
            int bin = (unsigned)k[q] >> 17;
            int pos = atomicAdd(&h[bin], 1);
            csrl[pos] = (int)(((unsigned)w[q] << 17) | ((unsigned)k[q] & 0x1FFFFu));
        }
    __syncthreads();

    // --- phase B: pull over LDS CSR (verified 8-deep gather loop) ---
    int hw = t >> 5, lane = t & 31;
    for (int q = 0; q < 4; ++q) {
        int rl = hw * 4 + q;
        int rowg = b * 128 + rl;
        if (rowg >= N_NODES) break;
        int j = rs[rl], endr = rs[rl + 1];
        float4 acc = make_float4(0.f, 0.f, 0.f, 0.f);
        for (; j + 7 < endr; j += 8) {
            int p0 = csrl[j],     p1 = csrl[j + 1], p2 = csrl[j + 2], p3 = csrl[j + 3];
            int p4 = csrl[j + 4], p5 = csrl[j + 5], p6 = csrl[j + 6], p7 = csrl[j + 7];
            ushort4 m0 = reinterpret_cast<const ushort4*>(xbf + (size_t)(p0 & 0x1FFFF) * DIM)[lane];
            ushort4 m1 = reinterpret_cast<const ushort4*>(xbf + (size_t)(p1 & 0x1FFFF) * DIM)[lane];
            ushort4 m2 = reinterpret_cast<const ushort4*>(xbf + (size_t)(p2 & 0x1FFFF) * DIM)[lane];
            ushort4 m3 = reinterpret_cast<const ushort4*>(xbf + (size_t)(p3 & 0x1FFFF) * DIM)[lane];
            ushort4 m4 = reinterpret_cast<const ushort4*>(xbf + (size_t)(p4 & 0x1FFFF) * DIM)[lane];
            ushort4 m5 = reinterpret_cast<const ushort4*>(xbf + (size_t)(p5 & 0x1FFFF) * DIM)[lane];
            ushort4 m6 = reinterpret_cast<const ushort4*>(xbf + (size_t)(p6 & 0x1FFFF) * DIM)[lane];
            ushort4 m7 = reinterpret_cast<const ushort4*>(xbf + (size_t)(p7 & 0x1FFFF) * DIM)[lane];
            float v0 = bf2f((unsigned short)((unsigned)p0 >> 17 << 1 >> 1));
            // NOTE: value bits were stored as bf16<<17 with sign 0; unpack:
            v0 = __uint_as_float(((unsigned)p0 >> 17) << 16);
            float v1 = __uint_as_float(((unsigned)p1 >> 17) << 16);
            float v2 = __uint_as_float(((unsigned)p2 >> 17) << 16);
            float v3 = __uint_as_float(((unsigned)p3 >> 17) << 16);
            float v4 = __uint_as_float(((unsigned)p4 >> 17) << 16);
            float v5 = __uint_as_float(((unsigned)p5 >> 17) << 16);
            float v6 = __uint_as_float(((unsigned)p6 >> 17) << 16);
            float v7 = __uint_as_float(((unsigned)p7 >> 17) << 16);
            acc.x += v0 * bf2f(m0.x) + v1 * bf2f(m1.x) + v2 * bf2f(m2.x) + v3 * bf2f(m3.x)
                   + v4 * bf2f(m4.x) + v5 * bf2f(m5.x) + v6 * bf2f(m6.x) + v7 * bf2f(m7.x);
            acc.y += v0 * bf2f(m0.y) + v1 * bf2f(m1.y) + v2 * bf2f(m2.y) + v3 * bf2f(m3.y)
                   + v4 * bf2f(m4.y) + v5 * bf2f(m5.y) + v6 * bf2f(m6.y) + v7 * bf2f(m7.y);
            acc.z += v0 * bf2f(m0.z) + v1 * bf2f(m1.z) + v2 * bf2f(m2.z) + v3 * bf2f(m3.z)
                   + v4 * bf2f(m4.z) + v5 * bf2f(m5.z) + v6 * bf2f(m6.z) + v7 * bf2f(m7.z);
            acc.w += v0 * bf2f(m0.w) + v1 * bf2f(m1.w) + v2 * bf2f(m2.w) + v3 * bf2f(m3.w)
                   + v4 * bf2f(m4.w) + v5 * bf2f(m5.w) + v6 * bf2f(m6.w) + v7 * bf2f(m7.w);
        }
        for (; j < endr; ++j) {
            int p0 = csrl[j];
            float v0 = __uint_as_float(((unsigned)p0 >> 17) << 16);
            ushort4 m0 = reinterpret_cast<const ushort4*>(xbf + (size_t)(p0 & 0x1FFFF) * DIM)[lane];
            acc.x += v0 * bf2f(m0.x);
            acc.y += v0 * bf2f(m0.y);
            acc.z += v0 * bf2f(m0.z);
            acc.w += v0 * bf2f(m0.w);
        }

        if (MODE == 0) {
            ushort4 o;
            o.x = f2bf(acc.x); o.y = f2bf(acc.y); o.z = f2bf(acc.z); o.w = f2bf(acc.w);
            reinterpret_cast<ushort4*>((ushort*)outp + (size_t)rowg * DIM)[lane] = o;
        } else {
            const float4* egorow = (rowg < NUM_SYM)
                ? reinterpret_cast<const float4*>(sym  + (size_t)rowg * DIM)
                : reinterpret_cast<const float4*>(herb + (size_t)(rowg - NUM_SYM) * DIM);
            float4 g = egorow[lane];
            ushort4 a = reinterpret_cast<const ushort4*>(e1bf + (size_t)rowg * DIM)[lane];
            const float s = 1.0f / 3.0f;
            floatx4 o;
            o.x = (g.x + bf2f(a.x) + acc.x) * s;
            o.y = (g.y + bf2f(a.y) + acc.y) * s;
            o.z = (g.z + bf2f(a.z) + acc.z) * s;
            o.w = (g.w + bf2f(a.w) + acc.w) * s;
            __builtin_nontemporal_store(o,
                reinterpret_cast<floatx4*>((float*)outp + (size_t)rowg * DIM) + lane);
        }
    }
}

// ---------------- fallback (round-1 verified atomic path) ----------------
__global__ __launch_bounds__(256) void spmm_scatter(
    const int* __restrict__ rows, const int* __restrict__ cols,
    const float* __restrict__ vals, int n_edges,
    const float* __restrict__ xa, const float* __restrict__ xb,
    float* __restrict__ out)
{
    int gid = blockIdx.x * 256 + threadIdx.x;
    int edge = gid >> 5;
    if (edge >= n_edges) return;
    int sub = gid & 31;
    int c = cols[edge];
    int r = rows[edge];
    float v = vals[edge];
    const float* xrow = (c < NUM_SYM) ? (xa + (size_t)c * DIM)
                                      : (xb + (size_t)(c - NUM_SYM) * DIM);
    float4 m = reinterpret_cast<const float4*>(xrow)[sub];
    float* o = out + (size_t)r * DIM + (size_t)sub * 4;
    unsafeAtomicAdd(o + 0, v * m.x);
    unsafeAtomicAdd(o + 1, v * m.y);
    unsafeAtomicAdd(o + 2, v * m.z);
    unsafeAtomicAdd(o + 3, v * m.w);
}

__global__ __launch_bounds__(256) void finalize_mean(
    const float* __restrict__ sym, const float* __restrict__ herb,
    const float* __restrict__ e1, float* __restrict__ out)
{
    int i = blockIdx.x * 256 + threadIdx.x;
    const int n4 = N_NODES * DIM / 4;
    if (i >= n4) return;
    const int sym4 = NUM_SYM * DIM / 4;
    float4 e = (i < sym4) ? reinterpret_cast<const float4*>(sym)[i]
                          : reinterpret_cast<const float4*>(herb)[i - sym4];
    float4 a = reinterpret_cast<const float4*>(e1)[i];
    float4 b = reinterpret_cast<float4*>(out)[i];
    const float s = 1.0f / 3.0f;
    float4 r;
    r.x = (e.x + a.x + b.x) * s;
    r.y = (e.y + a.y + b.y) * s;
    r.z = (e.z + a.z + b.z) * s;
    r.w = (e.w + a.w + b.w) * s;
    reinterpret_cast<float4*>(out)[i] = r;
}

extern "C" void kernel_launch(void* const* d_in, const int* in_sizes, int n_in,
                              void* d_out, int out_size, void* d_ws, size_t ws_size,
                              hipStream_t stream) {
    const float* sym  = (const float*)d_in[0];
    const float* herb = (const float*)d_in[1];
    const int*   rows = (const int*)d_in[2];
    const int*   cols = (const int*)d_in[3];
    const float* vals = (const float*)d_in[4];
    const int E = in_sizes[2];
    float* out = (float*)d_out;

    // fixed bucket capacity: 1.125x mean (+8 sigma), multiple of 32
    int CAP = (int)(((long)E / NB) * 9 / 8);
    CAP = (CAP + 31) / 32 * 32;
    if (CAP < 512) CAP = 512;

    // workspace layout (round-9-proven footprint, ~72.9MB at E=3.2M):
    //   xbf [25.6MB] | keys [NB*CAP*4] | bvals [NB*CAP*2] | e1bf [25.6MB] |
    //   cur [50KB padded]
    char* ws = (char*)d_ws;
    auto align256 = [](size_t x) { return (x + 255) & ~(size_t)255; };
    const size_t xbf_bytes  = (size_t)N_NODES * DIM * sizeof(ushort);   // 25.6 MB
    const size_t keys_off   = align256(xbf_bytes);
    const size_t bvals_off  = align256(keys_off + (size_t)NB * CAP * 4);
    const size_t e1_off     = align256(bvals_off + (size_t)NB * CAP * 2);
    const size_t cur_off    = align256(e1_off + xbf_bytes);
    const size_t required   = cur_off + (size_t)NB * PAD * 4;

    if (ws_size < required || E >= (1 << 22) || CAP > LDSCAP) {
        // fallback: verified round-1 atomic-scatter path (needs only 51.2MB e1)
        float* e1 = (float*)ws;
        const size_t e1_bytes = (size_t)N_NODES * DIM * sizeof(float);
        hipMemsetAsync(e1, 0, e1_bytes, stream);
        hipMemsetAsync(out, 0, e1_bytes, stream);
        const int spmm_blocks = (E * 32 + 255) / 256;
        spmm_scatter<<<spmm_blocks, 256, 0, stream>>>(rows, cols, vals, E, sym, herb, e1);
        spmm_scatter<<<spmm_blocks, 256, 0, stream>>>(rows, cols, vals, E,
                                                      e1, e1 + (size_t)NUM_SYM * DIM, out);
        const int n4 = N_NODES * DIM / 4;
        finalize_mean<<<(n4 + 255) / 256, 256, 0, stream>>>(sym, herb, e1, out);
        return;
    }

    ushort* xbf   = (ushort*)ws;
    int*    keys  = (int*)(ws + keys_off);
    ushort* bvals = (ushort*)(ws + bvals_off);
    ushort* e1bf  = (ushort*)(ws + e1_off);
    int*    cur   = (int*)(ws + cur_off);

    // --- fused gapped bucket scatter + bf16 conversion (one edge pass) ---
    hipMemsetAsync(cur, 0, (size_t)NB * PAD * 4, stream);
    const int EB   = (E + CHUNK - 1) / CHUNK;
    const int n4   = N_NODES * DIM / 4;
    const int CONV = (n4 + 1023) / 1024;
    scatter_and_convert<<<EB + CONV, 1024, 0, stream>>>(rows, cols, vals, E, CAP, EB,
                                                        sym, herb, cur, keys, bvals, xbf);

    // --- 2 propagation layers (fused in-LDS sort + pull) ---
    spmm_bucket<0><<<NB, 1024, 0, stream>>>(keys, bvals, cur, CAP, xbf,
                                            nullptr, nullptr, nullptr, e1bf);
    spmm_bucket<1><<<NB, 1024, 0, stream>>>(keys, bvals, cur, CAP, e1bf,
                                            sym, herb, e1bf, out);
}